// Round 7
// baseline (187.131 us; speedup 1.0000x reference)
//
#include <hip/hip_runtime.h>
#include <cstdint>
#include <cstddef>

// Problem constants (from reference: B,T,N = 512,1024,48)
constexpr int Bb = 512;
constexpr int Tt = 1024;
constexpr int Nn = 48;
constexpr int SG = 16;          // sequences per wave (MFMA N dimension here)
constexpr int NG = Bb / SG;     // 32 sequence-groups
constexpr int Cc = 64;          // time-chunks per sequence (grid = 2048 -> 2 waves/SIMD)
constexpr int Lc = Tt / Cc;     // 16 steps per chunk window
constexpr int Wb = 32;          // burn-in steps (validated in earlier session)
constexpr int TILE = 3328;      // 16 rows x 13 granules x 16 B (granule 12 = pad)
constexpr int NSLOT = 6;        // ring slots (19968 B LDS -> 8 blocks/CU)

typedef short bf16x8 __attribute__((ext_vector_type(8)));
typedef float f32x4  __attribute__((ext_vector_type(4)));
typedef unsigned int u32x4 __attribute__((ext_vector_type(4)));

__device__ __forceinline__ unsigned int bf16_rne(float x) {
    const unsigned int u = __float_as_uint(x);
    return ((u + 0x7FFFu + ((u >> 16) & 1u)) >> 16);
}
__device__ __forceinline__ unsigned int pack2(float lo, float hi) {
    return bf16_rne(lo) | (bf16_rne(hi) << 16);
}
__device__ __forceinline__ float safe_log(float x) {
    return __logf(fmaxf(x, 1e-30f));   // NaN/inf-proof (fmax discards NaN)
}
// Async global->LDS, 16 B per lane (dest = uniform base + lane*16).
__device__ __forceinline__ void gll16(const float* g, const char* l) {
    __builtin_amdgcn_global_load_lds(
        (const __attribute__((address_space(1))) void*)g,
        (__attribute__((address_space(3))) void*)l, 16, 0, 0);
}
// Asm ds_read: opaque to the compiler's waitcnt pass, so it cannot insert
// per-step vmcnt(0) drains to order it against global_load_lds (R6's ~900
// cyc/step flatline). We order it ourselves: counted vmcnt(8) at boundaries,
// lgkmcnt(0)+sched_barrier(0) before use (rule #18).
#define DSR(dst, ad) asm volatile("ds_read_b128 %0, %1" : "=&v"(dst) : "v"(ad))

// ---------------------------------------------------------------------------
// R7. Step math = R3/R6 verified operand-swap; two structural changes:
// (1) zero-shuffle B1: kc1 K-slot map  slot(q,d) -> state 32+4q+d (d<4),
//     d>=4 zero-padded on BOTH A and B. All 4 quads cover 4 states each ->
//     Bf1 = {pk20, pk21, 0, 0} from the lane's own regs. The only remaining
//     cross-lane op per step is the cb broadcast.
// (2) 6-slot LDS ring, stage distance 4-5, counted vmcnt(8) at each 2-step
//     boundary (m201/m218-verified pattern: builtin staging + asm waits +
//     asm ds_read). Counting is sound: in-loop VMEM = our gll16 only (gold
//     atomic drained by vmcnt(0) before the prologue), and LDS staging has
//     no registers to spill (R4/R5's unsoundness class is gone).
// XCD swizzle: gidx=(w&7)*4+((w>>3)&3), c=w>>5 puts all 64 chunks of 4
// seq-groups on one XCD; the 3x tile re-reads (window + 2 burn-in readers,
// whole grid co-resident) hit that XCD's L2 instead of HBM.
// ---------------------------------------------------------------------------
__launch_bounds__(64, 2)
__global__ void crf_fused(const float* __restrict__ pot,
                          const int*   __restrict__ ytrue,
                          const int*   __restrict__ lengths,
                          const float* __restrict__ trans,
                          float*       __restrict__ out)
{
    // 19968 B: trans (9216 B) during setup, then the 6-slot pot ring.
    __shared__ __align__(16) char smem_c[NSLOT * TILE];
    float* trans_lds = (float*)smem_c;

    const int lane = threadIdx.x;
    const int ln   = lane & 15;          // sequence index within group (MFMA N)
    const int q    = lane >> 4;          // quad
    const int w    = blockIdx.x;
    const int gidx = (w & 7) * 4 + ((w >> 3) & 3);   // XCD-coherent group map
    const int c    = w >> 5;                         // chunk 0..63
    const int s0   = gidx * SG;

    for (int i = lane; i < Nn * Nn; i += 64) trans_lds[i] = trans[i];
    __syncthreads();

    // ---- Gold-path score: sequence b = w>>2, quarter h = w&3 (any bijection
    // over blocks works; independent of the (gidx,c) map).
    {
        const int    b    = w >> 2;
        const int    h    = w & 3;
        const int    lenb = lengths[b];
        const int*   yrow = ytrue + (size_t)b * Tt;
        const float* prow = pot + (size_t)b * Tt * Nn;
        float gold = 0.0f;
#pragma unroll
        for (int k = 0; k < Tt / 256; ++k) {          // 4 iters x 64 lanes = 256 t
            const int   t    = h * (Tt / 4) + lane + 64 * k;
            const int   yt   = yrow[t];
            const int   ytm1 = yrow[(t > 0) ? (t - 1) : 0];
            const float u    = prow[(size_t)t * Nn + yt];
            const float tr   = trans_lds[ytm1 * Nn + yt];
            gold += (t < lenb) ? u : 0.0f;
            gold += (t >= 1 && t < lenb) ? tr : 0.0f;
        }
#pragma unroll
        for (int off = 32; off > 0; off >>= 1) gold += __shfl_xor(gold, off);
        if (lane == 0) atomicAdd(&out[b], -gold);
    }

    const int len_ln = lengths[s0 + ln];         // per-lane sequence length
    int lmax = len_ln;
#pragma unroll
    for (int off = 8; off > 0; off >>= 1) {
        const int o = __shfl_xor(lmax, off);
        lmax = (o > lmax) ? o : lmax;
    }

    const int start = (c == 0) ? 1 : c * Lc;
    if (c > 0 && start >= lmax) return;          // uniform exit (gold already done)
    const int end = ((c + 1) * Lc < lmax) ? (c + 1) * Lc : lmax;

    // A-operand fragments (E^T slices). K-slot->state bijection (same on B):
    //   kc0: slot (q,d) -> 16*(d>>2)+4q+(d&3)    => B0 = {pk00,pk01,pk10,pk11}
    //   kc1: slot (q,d<4) -> 32+4q+d, d>=4 -> 0  => B1 = {pk20,pk21,0,0}
    bf16x8 Wf[3][2];
#pragma unroll
    for (int nt = 0; nt < 3; ++nt)
#pragma unroll
        for (int kc = 0; kc < 2; ++kc)
#pragma unroll
            for (int d = 0; d < 8; ++d) {
                int i;
                if (kc == 0) {
                    i = 16 * (d >> 2) + 4 * q + (d & 3);
                } else {
                    i = (d < 4) ? (32 + 4 * q + d) : -1;
                }
                const float v = (i >= 0) ? __expf(trans_lds[i * Nn + nt * 16 + ln]) : 0.0f;
                Wf[nt][kc][d] = (short)bf16_rne(v);
            }

    const int slC = ln;                          // state-0 holder for seq ln

    // Per-lane pot row pointers (init only).
    const float* prow = pot + (size_t)(s0 + ln) * (Tt * Nn);
    const float* pp0 = prow + 0 * 16 + q * 4;
    const float* pp1 = prow + 1 * 16 + q * 4;
    const float* pp2 = prow + 2 * 16 + q * 4;

    int t0 = (c == 0) ? 1 : (start - Wb);
    if (t0 < 1) t0 = 1;                          // c=1,2: exact full recompute

    // ---- Init alpha from pot[t0-1], normalized so alpha[m][0] = 1.
    f32x4 pin0 = *(const f32x4*)(pp0 + (size_t)(t0 - 1) * Nn);
    f32x4 pin1 = *(const f32x4*)(pp1 + (size_t)(t0 - 1) * Nn);
    f32x4 pin2 = *(const f32x4*)(pp2 + (size_t)(t0 - 1) * Nn);
    const float cb0 = __shfl(pin0[0], slC);

    float gacc = (c == 0) ? cb0 : 0.0f;          // per-lane (seq = ln)
    f32x4 prev0, prev1, prev2;
#pragma unroll
    for (int r = 0; r < 4; ++r) {
        prev0[r] = __expf(pin0[r] - cb0);
        prev1[r] = __expf(pin1[r] - cb0);
        prev2[r] = __expf(pin2[r] - cb0);
    }

    unsigned int pk00 = pack2(prev0[0], prev0[1]);
    unsigned int pk01 = pack2(prev0[2], prev0[3]);
    unsigned int pk10 = pack2(prev1[0], prev1[1]);
    unsigned int pk11 = pack2(prev1[2], prev1[3]);
    unsigned int pk20 = pack2(prev2[0], prev2[1]);
    unsigned int pk21 = pack2(prev2[2], prev2[3]);
    bf16x8 Bf0 = __builtin_bit_cast(bf16x8, (u32x4){pk00, pk01, pk10, pk11});
    bf16x8 Bf1 = __builtin_bit_cast(bf16x8, (u32x4){pk20, pk21, 0u, 0u});

    // ---- Staging granule map: instruction i, lane l -> granule g = 64i+l;
    // row s = g/13, col cg = min(g%13, 11) (col 12 pad = dup). LDS dest is
    // linear; the padded layout comes from this per-lane source map.
    const float* srcp[4];
#pragma unroll
    for (int i = 0; i < 4; ++i) {
        int g = 64 * i + lane;
        int s = g / 13;  if (s > 15) s = 15;
        int cg = g % 13; if (cg > 11) cg = 11;
        srcp[i] = pot + (size_t)(s0 + s) * (Tt * Nn) + 4 * cg;
    }

    // LDS byte offset of this lane's tile granule, as a raw 32-bit address
    // for the asm ds_reads.
    typedef __attribute__((address_space(3))) char as3char;
    const unsigned lbase  = (unsigned)(uintptr_t)(as3char*)smem_c;
    const unsigned adbase = lbase + (unsigned)((ln * 13 + q) * 16);

    __syncthreads();   // retire all trans_lds reads before the ring overwrites it

#define STAGE(tt, SLOT) do {                                                    \
        const size_t toff_ = (size_t)(((tt) < Tt) ? (tt) : (Tt - 1)) * Nn;      \
        char* lb_ = smem_c + (SLOT) * TILE;                                     \
        gll16(srcp[0] + toff_, lb_);                                            \
        gll16(srcp[1] + toff_, lb_ + 1024);                                     \
        gll16(srcp[2] + toff_, lb_ + 2048);                                     \
        if (lane < 16) gll16(srcp[3] + toff_, lb_ + 3072);                      \
    } while (0)

// Boundary before steps {KK,KK+1}: their tiles were issued 2 boundaries
// (4 steps, ~1200 cyc) ago. vmcnt(8) retires exactly the oldest 8 ops
// (tiles KK,KK+1); the 8 newest (tiles KK+2,KK+3) stay in flight. Then
// issue tiles KK+4,KK+5 into slots consumed 2+ steps ago.
#define BOUNDARY(KK) do {                                                       \
        asm volatile("s_waitcnt vmcnt(8)");                                     \
        __builtin_amdgcn_sched_barrier(0);                                      \
        STAGE(t0 + (KK) + 4, ((KK) + 4) % NSLOT);                               \
        STAGE(t0 + (KK) + 5, ((KK) + 5) % NSLOT);                               \
    } while (0)

    float rrp = 1.0f;                            // deferred renorm carry

    // Prologue: drain everything (gold atomic included) so vmcnt counting is
    // exact, then issue tiles t0..t0+3 into slots 0..3.
    asm volatile("s_waitcnt vmcnt(0)");
    STAGE(t0 + 0, 0);
    STAGE(t0 + 1, 1);
    STAGE(t0 + 2, 2);
    STAGE(t0 + 3, 3);

    const int ksteps = ((end - t0) + 5) / 6 * 6; // padded steps provably inert

#define CRF_STEP(KK, SLOT)                                                      \
    {                                                                           \
        const int t_ = t0 + (KK);                                               \
        f32x4 PA_, PB_, PC_;                                                    \
        const unsigned ad_ = adbase + (SLOT) * TILE;                            \
        DSR(PA_, ad_);                                                          \
        DSR(PB_, ad_ + 64u);                                                    \
        DSR(PC_, ad_ + 128u);                                                   \
        f32x4 z_ = {0.0f, 0.0f, 0.0f, 0.0f};                                    \
        f32x4 D0_ = __builtin_amdgcn_mfma_f32_16x16x32_bf16(Wf[0][0], Bf0, z_, 0, 0, 0); \
        f32x4 D1_ = __builtin_amdgcn_mfma_f32_16x16x32_bf16(Wf[1][0], Bf0, z_, 0, 0, 0); \
        f32x4 D2_ = __builtin_amdgcn_mfma_f32_16x16x32_bf16(Wf[2][0], Bf0, z_, 0, 0, 0); \
        D0_ = __builtin_amdgcn_mfma_f32_16x16x32_bf16(Wf[0][1], Bf1, D0_, 0, 0, 0); \
        D1_ = __builtin_amdgcn_mfma_f32_16x16x32_bf16(Wf[1][1], Bf1, D1_, 0, 0, 0); \
        D2_ = __builtin_amdgcn_mfma_f32_16x16x32_bf16(Wf[2][1], Bf1, D2_, 0, 0, 0); \
        asm volatile("s_waitcnt lgkmcnt(0)");                                   \
        __builtin_amdgcn_sched_barrier(0);                                      \
        f32x4 a0_, a1_, a2_;                                                    \
        _Pragma("unroll")                                                       \
        for (int r = 0; r < 4; ++r) {                                           \
            a0_[r] = D0_[r] * (__expf(PA_[r]) * rrp);                           \
            a1_[r] = D1_[r] * (__expf(PB_[r]) * rrp);                           \
            a2_[r] = D2_[r] * (__expf(PC_[r]) * rrp);                           \
        }                                                                       \
        const float cb_ = __shfl(a0_[0], slC);                                  \
        const float rr_ = __builtin_amdgcn_rcpf(fmaxf(cb_, 1e-30f));            \
        const float lg_ = safe_log(cb_);                                        \
        gacc += ((t_ >= start) && (t_ < end) && (t_ + 1 < len_ln)) ? lg_ : 0.0f; \
        const bool act_ = (t_ < len_ln);                                        \
        _Pragma("unroll")                                                       \
        for (int r = 0; r < 4; ++r) {                                           \
            prev0[r] = act_ ? a0_[r] : prev0[r];                                \
            prev1[r] = act_ ? a1_[r] : prev1[r];                                \
            prev2[r] = act_ ? a2_[r] : prev2[r];                                \
        }                                                                       \
        pk00 = pack2(prev0[0], prev0[1]);                                       \
        pk01 = pack2(prev0[2], prev0[3]);                                       \
        pk10 = pack2(prev1[0], prev1[1]);                                       \
        pk11 = pack2(prev1[2], prev1[3]);                                       \
        pk20 = pack2(prev2[0], prev2[1]);                                       \
        pk21 = pack2(prev2[2], prev2[3]);                                       \
        Bf0 = __builtin_bit_cast(bf16x8, (u32x4){pk00, pk01, pk10, pk11});      \
        Bf1 = __builtin_bit_cast(bf16x8, (u32x4){pk20, pk21, 0u, 0u});          \
        rrp = rr_;                                                              \
    }

    for (int k = 0; k < ksteps; k += 6) {
        BOUNDARY(k);     CRF_STEP(k + 0, 0); CRF_STEP(k + 1, 1);
        BOUNDARY(k + 2); CRF_STEP(k + 2, 2); CRF_STEP(k + 3, 3);
        BOUNDARY(k + 4); CRF_STEP(k + 4, 4); CRF_STEP(k + 5, 5);
    }
#undef CRF_STEP
#undef BOUNDARY
#undef STAGE

    asm volatile("s_waitcnt vmcnt(0)");          // drain trailing staging
                                                 // (LDS DMA must not outlive wave)

    // Chunk contribution; the unique "last" chunk adds the logsumexp.
    // (final rowsum is pre-division by the last active step's c, whose log
    //  was deliberately NOT added to gacc - exact telescoping.)
    float rs = prev0[0] + prev0[1] + prev0[2] + prev0[3]
             + prev1[0] + prev1[1] + prev1[2] + prev1[3]
             + prev2[0] + prev2[1] + prev2[2] + prev2[3];
    rs += __shfl_xor(rs, 16);
    rs += __shfl_xor(rs, 32);                    // full 48-state sum per lane

    const bool active_chunk = (c == 0) || (c * Lc < len_ln);
    const bool last = active_chunk && (len_ln <= (c + 1) * Lc);
    const float G = gacc + (last ? safe_log(rs) : 0.0f);
    if (lane < 16) atomicAdd(&out[s0 + ln], G);
}

extern "C" void kernel_launch(void* const* d_in, const int* in_sizes, int n_in,
                              void* d_out, int out_size, void* d_ws, size_t ws_size,
                              hipStream_t stream)
{
    const float* pot   = (const float*)d_in[0];
    const int*   ytrue = (const int*)  d_in[1];
    const int*   lens  = (const int*)  d_in[2];
    const float* trans = (const float*)d_in[3];
    float*       out   = (float*)d_out;

    hipMemsetAsync(out, 0, (size_t)out_size * sizeof(float), stream);
    crf_fused<<<dim3(NG * Cc), dim3(64), 0, stream>>>(pot, ytrue, lens, trans, out);
}

// Round 8
// 185.473 us; speedup vs baseline: 1.0089x; 1.0089x over previous
//
#include <hip/hip_runtime.h>
#include <cstdint>
#include <cstddef>

// Problem constants (from reference: B,T,N = 512,1024,48)
constexpr int Bb = 512;
constexpr int Tt = 1024;
constexpr int Nn = 48;
constexpr int SG = 16;          // sequences per wave (MFMA N dimension here)
constexpr int NG = Bb / SG;     // 32 sequence-groups
constexpr int Cc = 64;          // time-chunks per sequence (grid = 2048)
constexpr int Lc = Tt / Cc;     // 16 steps per chunk window
constexpr int Wb = 32;          // burn-in steps (validated in earlier session)
constexpr int TILE2 = 6400;     // 2-step tile: 16 rows x 25 granules x 16B (gran 24 = pad)
constexpr int NSLOT = 3;        // ring slots: 19200 B -> 8 blocks/CU

typedef short bf16x8 __attribute__((ext_vector_type(8)));
typedef float f32x4  __attribute__((ext_vector_type(4)));
typedef unsigned int u32x4 __attribute__((ext_vector_type(4)));

__device__ __forceinline__ unsigned int bf16_rne(float x) {
    const unsigned int u = __float_as_uint(x);
    return ((u + 0x7FFFu + ((u >> 16) & 1u)) >> 16);
}
__device__ __forceinline__ unsigned int pack2(float lo, float hi) {
    return bf16_rne(lo) | (bf16_rne(hi) << 16);
}
__device__ __forceinline__ float safe_log(float x) {
    return __logf(fmaxf(x, 1e-30f));   // NaN/inf-proof (fmax discards NaN)
}
// Async global->LDS, 16 B per lane (dest = uniform base + lane*16, linear).
__device__ __forceinline__ void gll16(const float* g, const char* l) {
    __builtin_amdgcn_global_load_lds(
        (const __attribute__((address_space(1))) void*)g,
        (__attribute__((address_space(3))) void*)l, 16, 0, 0);
}
// Asm ds_read (opaque to waitcnt pass); ordered by our own counted waits +
// lgkmcnt(0)+sched_barrier before use (rule #18).
#define DSR(dst, ad) asm volatile("ds_read_b128 %0, %1" : "=&v"(dst) : "v"(ad))

// ---------------------------------------------------------------------------
// R8. Step math = R7 (operand-swapped MFMA, zero-shuffle B1, per-lane renorm
// with deferred division). ONE variable changed: the staging access pattern.
//
// R0-R7 invariant: per-step wall ~2500-3750 cyc regardless of inner body;
// VALU+MFMA+LDS pipes account for <1000 -> the VMEM path is the wall, and
// every prior version scattered each pot access across 16 rows 196KB apart
// (16 discontiguous segments per instruction; 192B row-reads straddle 128B
// granules -> FETCH 1.7x compulsory).
//
// Fix: 2-step tiles staged TIME-CONTIGUOUSLY: per row 384B = exactly 3x128B
// granules (t0 even for c>0); lanes map 25-granules-per-row (24 data + 1 pad
// dup) so consecutive lanes read consecutive 16B of the SAME row (~2.6 rows,
// ~9 granules per instruction). LDS dest linear (HW rule); row stride 400B
// -> ds_read_b128 2-way bank aliasing only (free, m136).
// Ring of 3 pair-tiles; boundary per pair: vmcnt(7) waits for the tile
// issued 2 pairs (4 steps) earlier; then stage pair j+2.
// ---------------------------------------------------------------------------
__launch_bounds__(64, 2)
__global__ void crf_fused(const float* __restrict__ pot,
                          const int*   __restrict__ ytrue,
                          const int*   __restrict__ lengths,
                          const float* __restrict__ trans,
                          float*       __restrict__ out)
{
    // 19200 B: trans (9216 B) during setup, then the 3-slot pair-tile ring.
    __shared__ __align__(16) char smem_c[NSLOT * TILE2];
    float* trans_lds = (float*)smem_c;

    const int lane = threadIdx.x;
    const int ln   = lane & 15;          // sequence index within group (MFMA N)
    const int q    = lane >> 4;          // quad
    const int w    = blockIdx.x;
    const int gidx = (w & 7) * 4 + ((w >> 3) & 3);   // XCD-coherent group map
    const int c    = w >> 5;                         // chunk 0..63
    const int s0   = gidx * SG;

    for (int i = lane; i < Nn * Nn; i += 64) trans_lds[i] = trans[i];
    __syncthreads();

    // ---- Gold-path score: sequence b = w>>2, quarter h = w&3.
    {
        const int    b    = w >> 2;
        const int    h    = w & 3;
        const int    lenb = lengths[b];
        const int*   yrow = ytrue + (size_t)b * Tt;
        const float* prow = pot + (size_t)b * Tt * Nn;
        float gold = 0.0f;
#pragma unroll
        for (int k = 0; k < Tt / 256; ++k) {          // 4 iters x 64 lanes = 256 t
            const int   t    = h * (Tt / 4) + lane + 64 * k;
            const int   yt   = yrow[t];
            const int   ytm1 = yrow[(t > 0) ? (t - 1) : 0];
            const float u    = prow[(size_t)t * Nn + yt];
            const float tr   = trans_lds[ytm1 * Nn + yt];
            gold += (t < lenb) ? u : 0.0f;
            gold += (t >= 1 && t < lenb) ? tr : 0.0f;
        }
#pragma unroll
        for (int off = 32; off > 0; off >>= 1) gold += __shfl_xor(gold, off);
        if (lane == 0) atomicAdd(&out[b], -gold);
    }

    const int len_ln = lengths[s0 + ln];         // per-lane sequence length
    int lmax = len_ln;
#pragma unroll
    for (int off = 8; off > 0; off >>= 1) {
        const int o = __shfl_xor(lmax, off);
        lmax = (o > lmax) ? o : lmax;
    }

    const int start = (c == 0) ? 1 : c * Lc;
    if (c > 0 && start >= lmax) return;          // uniform exit (gold already done)
    const int end = ((c + 1) * Lc < lmax) ? (c + 1) * Lc : lmax;

    // A-operand fragments (E^T slices). K-slot->state bijection (same on B):
    //   kc0: slot (q,d) -> 16*(d>>2)+4q+(d&3)    => B0 = {pk00,pk01,pk10,pk11}
    //   kc1: slot (q,d<4) -> 32+4q+d, d>=4 -> 0  => B1 = {pk20,pk21,0,0}
    bf16x8 Wf[3][2];
#pragma unroll
    for (int nt = 0; nt < 3; ++nt)
#pragma unroll
        for (int kc = 0; kc < 2; ++kc)
#pragma unroll
            for (int d = 0; d < 8; ++d) {
                int i;
                if (kc == 0) {
                    i = 16 * (d >> 2) + 4 * q + (d & 3);
                } else {
                    i = (d < 4) ? (32 + 4 * q + d) : -1;
                }
                const float v = (i >= 0) ? __expf(trans_lds[i * Nn + nt * 16 + ln]) : 0.0f;
                Wf[nt][kc][d] = (short)bf16_rne(v);
            }

    const int slC = ln;                          // state-0 holder for seq ln

    // Per-lane pot row pointers (init only).
    const float* prow = pot + (size_t)(s0 + ln) * (Tt * Nn);
    const float* pp0 = prow + 0 * 16 + q * 4;
    const float* pp1 = prow + 1 * 16 + q * 4;
    const float* pp2 = prow + 2 * 16 + q * 4;

    int t0 = (c == 0) ? 1 : (start - Wb);
    if (t0 < 1) t0 = 1;                          // c=1,2: exact full recompute

    // ---- Init alpha from pot[t0-1], normalized so alpha[m][0] = 1.
    f32x4 pin0 = *(const f32x4*)(pp0 + (size_t)(t0 - 1) * Nn);
    f32x4 pin1 = *(const f32x4*)(pp1 + (size_t)(t0 - 1) * Nn);
    f32x4 pin2 = *(const f32x4*)(pp2 + (size_t)(t0 - 1) * Nn);
    const float cb0 = __shfl(pin0[0], slC);

    float gacc = (c == 0) ? cb0 : 0.0f;          // per-lane (seq = ln)
    f32x4 prev0, prev1, prev2;
#pragma unroll
    for (int r = 0; r < 4; ++r) {
        prev0[r] = __expf(pin0[r] - cb0);
        prev1[r] = __expf(pin1[r] - cb0);
        prev2[r] = __expf(pin2[r] - cb0);
    }

    unsigned int pk00 = pack2(prev0[0], prev0[1]);
    unsigned int pk01 = pack2(prev0[2], prev0[3]);
    unsigned int pk10 = pack2(prev1[0], prev1[1]);
    unsigned int pk11 = pack2(prev1[2], prev1[3]);
    unsigned int pk20 = pack2(prev2[0], prev2[1]);
    unsigned int pk21 = pack2(prev2[2], prev2[3]);
    bf16x8 Bf0 = __builtin_bit_cast(bf16x8, (u32x4){pk00, pk01, pk10, pk11});
    bf16x8 Bf1 = __builtin_bit_cast(bf16x8, (u32x4){pk20, pk21, 0u, 0u});

    // ---- Staging source map (time-contiguous): slot-granule sg = 64i+lane;
    // row = sg/25, chunk cg = min(sg%25, 23) -> the lane reads bytes
    // [cg*16, cg*16+16) of row's 2-step run starting at t_pair*192.
    // Consecutive lanes = consecutive 16B of the SAME row.
    const float* srcp2[7];
#pragma unroll
    for (int i = 0; i < 7; ++i) {
        int sg = 64 * i + lane;
        int rr_ = sg / 25;  if (rr_ > 15) rr_ = 15;   // lanes>=16 of inst 6: unused
        int cg  = sg % 25;  if (cg > 23) cg = 23;     // pad granule = dup of 23
        srcp2[i] = pot + (size_t)(s0 + rr_) * (Tt * Nn) + 4 * cg;
    }

    // LDS address of this lane's data: row ln at stride 400B; step parity s
    // adds 192B; nt groups at +0/+64/+128; quad at +16q.
    typedef __attribute__((address_space(3))) char as3char;
    const unsigned lbase  = (unsigned)(uintptr_t)(as3char*)smem_c;
    const unsigned adbase = lbase + (unsigned)(ln * 400 + q * 16);

    __syncthreads();   // retire all trans_lds reads before the ring overwrites it

#define STAGE2(J, SLOT) do {                                                    \
        int tp_ = t0 + 2 * (J); if (tp_ > Tt - 2) tp_ = Tt - 2;                 \
        const size_t fo_ = (size_t)tp_ * Nn;                                    \
        char* lb_ = smem_c + (SLOT) * TILE2;                                    \
        gll16(srcp2[0] + fo_, lb_);                                             \
        gll16(srcp2[1] + fo_, lb_ + 1024);                                      \
        gll16(srcp2[2] + fo_, lb_ + 2048);                                      \
        gll16(srcp2[3] + fo_, lb_ + 3072);                                      \
        gll16(srcp2[4] + fo_, lb_ + 4096);                                      \
        gll16(srcp2[5] + fo_, lb_ + 5120);                                      \
        if (lane < 16) gll16(srcp2[6] + fo_, lb_ + 6144);                       \
    } while (0)

// Boundary before pair J: its tile was issued 2 pairs (4 steps) earlier.
// vmcnt(7) = exactly one tile (7 ops) still outstanding after the wait;
// then stage pair J+2 into the slot consumed at pair J-1.
#define BOUNDARY(J, SLOT_NEXT) do {                                             \
        asm volatile("s_waitcnt vmcnt(7)");                                     \
        __builtin_amdgcn_sched_barrier(0);                                      \
        STAGE2((J) + 2, SLOT_NEXT);                                             \
    } while (0)

    float rrp = 1.0f;                            // deferred renorm carry

    // Prologue: drain (gold atomics) so vmcnt counting is exact, then issue
    // pair-tiles 0,1 into slots 0,1.
    asm volatile("s_waitcnt vmcnt(0)");
    STAGE2(0, 0);
    STAGE2(1, 1);

    // Pairs, rounded up to a multiple of 3 (ring phase); padded steps are
    // provably inert: rows with len<=end freeze (act gate); rows with
    // len>end never have prev/rowsum consumed; gacc gated t<end.
    const int npr = ((((end - t0) + 1) >> 1) + 2) / 3 * 3;

#define CRF_STEP(KK, SLOT, SOFF)                                                \
    {                                                                           \
        const int t_ = t0 + (KK);                                               \
        f32x4 PA_, PB_, PC_;                                                    \
        const unsigned ad_ = adbase + (SLOT) * TILE2 + (SOFF);                  \
        DSR(PA_, ad_);                                                          \
        DSR(PB_, ad_ + 64u);                                                    \
        DSR(PC_, ad_ + 128u);                                                   \
        f32x4 z_ = {0.0f, 0.0f, 0.0f, 0.0f};                                    \
        f32x4 D0_ = __builtin_amdgcn_mfma_f32_16x16x32_bf16(Wf[0][0], Bf0, z_, 0, 0, 0); \
        f32x4 D1_ = __builtin_amdgcn_mfma_f32_16x16x32_bf16(Wf[1][0], Bf0, z_, 0, 0, 0); \
        f32x4 D2_ = __builtin_amdgcn_mfma_f32_16x16x32_bf16(Wf[2][0], Bf0, z_, 0, 0, 0); \
        D0_ = __builtin_amdgcn_mfma_f32_16x16x32_bf16(Wf[0][1], Bf1, D0_, 0, 0, 0); \
        D1_ = __builtin_amdgcn_mfma_f32_16x16x32_bf16(Wf[1][1], Bf1, D1_, 0, 0, 0); \
        D2_ = __builtin_amdgcn_mfma_f32_16x16x32_bf16(Wf[2][1], Bf1, D2_, 0, 0, 0); \
        asm volatile("s_waitcnt lgkmcnt(0)");                                   \
        __builtin_amdgcn_sched_barrier(0);                                      \
        f32x4 a0_, a1_, a2_;                                                    \
        _Pragma("unroll")                                                       \
        for (int r = 0; r < 4; ++r) {                                           \
            a0_[r] = D0_[r] * (__expf(PA_[r]) * rrp);                           \
            a1_[r] = D1_[r] * (__expf(PB_[r]) * rrp);                           \
            a2_[r] = D2_[r] * (__expf(PC_[r]) * rrp);                           \
        }                                                                       \
        const float cb_ = __shfl(a0_[0], slC);                                  \
        const float rr_ = __builtin_amdgcn_rcpf(fmaxf(cb_, 1e-30f));            \
        const float lg_ = safe_log(cb_);                                        \
        gacc += ((t_ >= start) && (t_ < end) && (t_ + 1 < len_ln)) ? lg_ : 0.0f; \
        const bool act_ = (t_ < len_ln);                                        \
        _Pragma("unroll")                                                       \
        for (int r = 0; r < 4; ++r) {                                           \
            prev0[r] = act_ ? a0_[r] : prev0[r];                                \
            prev1[r] = act_ ? a1_[r] : prev1[r];                                \
            prev2[r] = act_ ? a2_[r] : prev2[r];                                \
        }                                                                       \
        pk00 = pack2(prev0[0], prev0[1]);                                       \
        pk01 = pack2(prev0[2], prev0[3]);                                       \
        pk10 = pack2(prev1[0], prev1[1]);                                       \
        pk11 = pack2(prev1[2], prev1[3]);                                       \
        pk20 = pack2(prev2[0], prev2[1]);                                       \
        pk21 = pack2(prev2[2], prev2[3]);                                       \
        Bf0 = __builtin_bit_cast(bf16x8, (u32x4){pk00, pk01, pk10, pk11});      \
        Bf1 = __builtin_bit_cast(bf16x8, (u32x4){pk20, pk21, 0u, 0u});          \
        rrp = rr_;                                                              \
    }

    for (int j = 0; j < npr; j += 3) {
        BOUNDARY(j, 2);
        CRF_STEP(2 * j + 0, 0, 0);   CRF_STEP(2 * j + 1, 0, 192);
        BOUNDARY(j + 1, 0);
        CRF_STEP(2 * j + 2, 1, 0);   CRF_STEP(2 * j + 3, 1, 192);
        BOUNDARY(j + 2, 1);
        CRF_STEP(2 * j + 4, 2, 0);   CRF_STEP(2 * j + 5, 2, 192);
    }
#undef CRF_STEP
#undef BOUNDARY
#undef STAGE2

    asm volatile("s_waitcnt vmcnt(0)");          // drain trailing staging

    // Chunk contribution; the unique "last" chunk adds the logsumexp.
    float rs = prev0[0] + prev0[1] + prev0[2] + prev0[3]
             + prev1[0] + prev1[1] + prev1[2] + prev1[3]
             + prev2[0] + prev2[1] + prev2[2] + prev2[3];
    rs += __shfl_xor(rs, 16);
    rs += __shfl_xor(rs, 32);                    // full 48-state sum per lane

    const bool active_chunk = (c == 0) || (c * Lc < len_ln);
    const bool last = active_chunk && (len_ln <= (c + 1) * Lc);
    const float G = gacc + (last ? safe_log(rs) : 0.0f);
    if (lane < 16) atomicAdd(&out[s0 + ln], G);
}

extern "C" void kernel_launch(void* const* d_in, const int* in_sizes, int n_in,
                              void* d_out, int out_size, void* d_ws, size_t ws_size,
                              hipStream_t stream)
{
    const float* pot   = (const float*)d_in[0];
    const int*   ytrue = (const int*)  d_in[1];
    const int*   lens  = (const int*)  d_in[2];
    const float* trans = (const float*)d_in[3];
    float*       out   = (float*)d_out;

    hipMemsetAsync(out, 0, (size_t)out_size * sizeof(float), stream);
    crf_fused<<<dim3(NG * Cc), dim3(64), 0, stream>>>(pot, ytrue, lens, trans, out);
}